// Round 7
// baseline (144.482 us; speedup 1.0000x reference)
//
#include <hip/hip_runtime.h>

#define IN_C 64
#define OUT_C 16
#define EA_D 8

typedef float f32x4 __attribute__((ext_vector_type(4)));
typedef float f32x2 __attribute__((ext_vector_type(2)));

// DPP cross-lane move, VALU-speed (no DS latency, no lgkmcnt):
//   0x141 row_half_mirror   (i -> i^7 within each 8-lane half)
//   0x4E  quad_perm [2,3,0,1]  (i -> i^2)
//   0xB1  quad_perm [1,0,3,2]  (i -> i^1)
// XOR masks {7,2,1} generate the full 8-group -> complete butterfly over
// each aligned 8-lane group for max and sum.
#define DPPF(x, ctrl) \
    __uint_as_float((unsigned)__builtin_amdgcn_update_dpp( \
        0, (int)__float_as_uint(x), (ctrl), 0xF, 0xF, true))

__device__ __forceinline__ void atomic_add_f32(float* p, float v) {
#if defined(__HIP_PLATFORM_AMD__) || defined(__AMDGCN__)
    unsafeAtomicAdd(p, v);   // global_atomic_add_f32, no CAS loop
#else
    atomicAdd(p, v);
#endif
}

// Packed f32x2 atomic add. Round-6 lesson: raw asm "global_atomic_pk_add_f32"
// does NOT assemble on gfx950. Use the intrinsic route with __has_builtin
// guards (clang gates target builtins by feature) so this compiles whether
// or not CDNA4 kept the v2f32 pk-fadd. Fallback = 2 scalar atomics (same op
// count as the measured 128.97us baseline -> worst case ~neutral).
__device__ __forceinline__ void atomic_pk_add(float* p, f32x2 v) {
#if defined(__AMDGCN__) && __has_builtin(__builtin_amdgcn_flat_atomic_fadd_v2f32)
    __builtin_amdgcn_flat_atomic_fadd_v2f32((f32x2*)p, v);
#elif defined(__AMDGCN__) && __has_builtin(__builtin_amdgcn_global_atomic_fadd_v2f32)
    typedef __attribute__((address_space(1))) f32x2 gbl_f32x2;
    __builtin_amdgcn_global_atomic_fadd_v2f32((gbl_f32x2*)(void*)p, v);
#else
    atomic_add_f32(p,     v.x);
    atomic_add_f32(p + 1, v.y);
#endif
}

// ---------------- h = x @ lin_w + lin_b  (also zeroes out[]) ----------------
// ROUND-0 VERSION, verbatim -- part of the measured-best 128.97us config.
// h-line is closed: r5 proved halving DS/output at equal occupancy changes
// nothing (not DS-issue-bound); r3/r4 proved bigger tiles let the compiler
// pipeline VGPRs into an occupancy cliff (+11/+12us).
__global__ __launch_bounds__(256) void h_kernel(
    const float* __restrict__ x,
    const float* __restrict__ lin_w,   // [64,16]
    const float* __restrict__ lin_b,   // [16]
    float* __restrict__ h,             // [N,16]
    float* __restrict__ out,           // [N,16] zero-init
    int n)
{
    __shared__ float s_x [16][IN_C + 4];   // stride 68 floats: 16B-aligned rows
    __shared__ float s_wt[16][IN_C + 4];   // transposed W: s_wt[c][k]

    const int t = threadIdx.x;
    const int nodeBase = blockIdx.x * 16;

    // zero out[] early: store latency hides under the FMA loop below
    {
        const int idx = nodeBase * OUT_C + t;      // 256 consecutive elements
        if (idx < n * OUT_C) out[idx] = 0.0f;
    }

    // stage transposed weights (one-time, conflicts irrelevant)
    for (int i = t; i < IN_C * OUT_C; i += 256)
        s_wt[i & 15][i >> 4] = lin_w[i];

    {
        const int lr = t >> 4;            // row 0..15
        const int k4 = (t & 15) * 4;      // col 0,4,...,60
        const int node = nodeBase + lr;
        float4 v = make_float4(0.f, 0.f, 0.f, 0.f);
        if (node < n) v = *(const float4*)(x + (size_t)node * IN_C + k4);
        *(float4*)(&s_x[lr][k4]) = v;
    }
    __syncthreads();

    const int lr = t >> 4;
    const int c  = t & 15;
    const int node = nodeBase + lr;
    if (node < n) {
        float acc = lin_b[c];
        #pragma unroll
        for (int k4 = 0; k4 < IN_C; k4 += 4) {
            const float4 xv = *(const float4*)(&s_x [lr][k4]);  // broadcast in quad
            const float4 wv = *(const float4*)(&s_wt[c ][k4]);  // <=2-way conflict (free)
            acc = fmaf(xv.x, wv.x, acc);
            acc = fmaf(xv.y, wv.y, acc);
            acc = fmaf(xv.z, wv.z, acc);
            acc = fmaf(xv.w, wv.w, acc);
        }
        h[(size_t)node * OUT_C + c] = acc;
    }
}

// ---------------- per-edge fused kernel: 8 lanes/edge, 2 ch/lane ----------------
// r2 proved edge is NOT instruction-bound (-25 DS ops/lane -> only -2us).
// This tests the atomic-op-rate hypothesis: pk-fadd halves the atomic count
// (6.4M -> 3.2M ops) and wave count (100k -> 50k) while keeping the gather
// pattern identical (8 lanes x 8B still cover one 64B h line).
__global__ __launch_bounds__(256) void edge_kernel(
    const int*   __restrict__ edge_index,  // [2,E]
    const float* __restrict__ edge_attr,   // [E,8]
    const float* __restrict__ ea_w,        // [8,16]
    const float* __restrict__ ea_b,        // [16]
    const float* __restrict__ w1,          // [16]
    const float* __restrict__ b1,          // [16]
    const float* __restrict__ w2,          // [16]
    const float* __restrict__ b2,          // [1]
    const float* __restrict__ h,           // [N,16]
    float*       __restrict__ out,         // [N,16]
    int E)
{
    __shared__ float s_eawT[16][12];   // row c = ea_w[:,c]; 48B rows, halves 16B-aligned
    __shared__ float s_eab[OUT_C];

    const int t = threadIdx.x;
    if (t < 128)                s_eawT[t & 15][t >> 4] = ea_w[(t >> 4) * OUT_C + (t & 15)];
    else if (t < 128 + OUT_C)   s_eab[t - 128] = ea_b[t - 128];
    __syncthreads();

    const int gid = blockIdx.x * 256 + t;
    const int e  = gid >> 3;       // 8 lanes per edge (aligned groups)
    const int c0 = (gid & 7) * 2;  // channel pair: 0,2,...,14
    if (e >= E) return;

    const int row = edge_index[e] - 1;     // edge_index[0][e] - 1
    const int col = edge_index[E + e];     // edge_index[1][e]

    // full 32B row per lane (same line within the 8-lane group -> broadcast)
    const f32x4* ap = (const f32x4*)(edge_attr + (size_t)e * EA_D);
    const f32x4 a0 = ap[0], a1 = ap[1];

    // gather: 8 lanes x 8B cover one 64B line of h
    const f32x2 hv = *(const f32x2*)(h + (size_t)col * OUT_C + c0);

    // d for both channels; k ascending (agg bit-exact vs baseline)
    const f32x4 u0 = *(const f32x4*)(&s_eawT[c0    ][0]);
    const f32x4 u4 = *(const f32x4*)(&s_eawT[c0    ][4]);
    const f32x4 v0 = *(const f32x4*)(&s_eawT[c0 + 1][0]);
    const f32x4 v4 = *(const f32x4*)(&s_eawT[c0 + 1][4]);
    const f32x2 bb = *(const f32x2*)(&s_eab[c0]);

    float d0 = bb.x, d1 = bb.y;
    d0 = fmaf(a0.x, u0.x, d0);  d1 = fmaf(a0.x, v0.x, d1);
    d0 = fmaf(a0.y, u0.y, d0);  d1 = fmaf(a0.y, v0.y, d1);
    d0 = fmaf(a0.z, u0.z, d0);  d1 = fmaf(a0.z, v0.z, d1);
    d0 = fmaf(a0.w, u0.w, d0);  d1 = fmaf(a0.w, v0.w, d1);
    d0 = fmaf(a1.x, u4.x, d0);  d1 = fmaf(a1.x, v4.x, d1);
    d0 = fmaf(a1.y, u4.y, d0);  d1 = fmaf(a1.y, v4.y, d1);
    d0 = fmaf(a1.z, u4.z, d0);  d1 = fmaf(a1.z, v4.z, d1);
    d0 = fmaf(a1.w, u4.w, d0);  d1 = fmaf(a1.w, v4.w, d1);

    const float agg0 = hv.x * d0;
    const float agg1 = hv.y * d1;

    // scores for both channels (uniform scalar weight loads)
    float s0 = b2[0], s1 = b2[0];
    #pragma unroll
    for (int j = 0; j < OUT_C; ++j) {
        const float w1j = w1[j], b1j = b1[j], w2j = w2[j];
        const float hm0 = fmaf(agg0, w1j, b1j);
        const float hm1 = fmaf(agg1, w1j, b1j);
        s0 = fmaf(fmaxf(hm0, 0.0f), w2j, s0);
        s1 = fmaf(fmaxf(hm1, 0.0f), w2j, s1);
    }

    // softmax over 16 channels = local pair + 8-lane DPP butterfly
    float m = fmaxf(s0, s1);
    m = fmaxf(m, DPPF(m, 0x141));
    m = fmaxf(m, DPPF(m, 0x4E));
    m = fmaxf(m, DPPF(m, 0xB1));

    const float p0 = __expf(s0 - m);
    const float p1 = __expf(s1 - m);
    float den = p0 + p1;
    den += DPPF(den, 0x141);
    den += DPPF(den, 0x4E);
    den += DPPF(den, 0xB1);

    const float r = __builtin_amdgcn_rcpf(den);
    const f32x2 val = {agg0 * (p0 * r), agg1 * (p1 * r)};

    // one packed atomic per lane (or 2 scalar fallback): 8B aligned (c0 even)
    atomic_pk_add(out + (size_t)row * OUT_C + c0, val);
}

extern "C" void kernel_launch(void* const* d_in, const int* in_sizes, int n_in,
                              void* d_out, int out_size, void* d_ws, size_t ws_size,
                              hipStream_t stream)
{
    const float* x          = (const float*)d_in[0];
    const int*   edge_index = (const int*)  d_in[1];
    const float* edge_attr  = (const float*)d_in[2];
    const float* lin_w      = (const float*)d_in[3];
    const float* lin_b      = (const float*)d_in[4];
    const float* ea_w       = (const float*)d_in[5];
    const float* ea_b       = (const float*)d_in[6];
    const float* attn_w1    = (const float*)d_in[7];
    const float* attn_b1    = (const float*)d_in[8];
    const float* attn_w2    = (const float*)d_in[9];
    const float* attn_b2    = (const float*)d_in[10];

    const int n = in_sizes[0] / IN_C;      // 100000
    const int E = in_sizes[1] / 2;         // 400000

    float* h   = (float*)d_ws;             // [N,16] = 6.4 MB
    float* out = (float*)d_out;

    // h_kernel zeroes out[] (grid covers every out element exactly once)
    h_kernel<<<(n + 15) / 16, 256, 0, stream>>>(x, lin_w, lin_b, h, out, n);

    // 8 lanes per edge
    const long long threads = (long long)E * 8;
    edge_kernel<<<(int)((threads + 255) / 256), 256, 0, stream>>>(
        edge_index, edge_attr, ea_w, ea_b,
        attn_w1, attn_b1, attn_w2, attn_b2,
        h, out, E);
}

// Round 9
// 128.651 us; speedup vs baseline: 1.1230x; 1.1230x over previous
//
#include <hip/hip_runtime.h>

#define IN_C 64
#define OUT_C 16
#define EA_D 8

typedef float f32x4 __attribute__((ext_vector_type(4)));

// DPP cross-lane move, VALU-speed (no DS latency, no lgkmcnt):
//   0x140 row_mirror        (i -> 15-i within each 16-lane row)
//   0x141 row_half_mirror   (i -> (i&8) | (7-(i&7)))
//   0x4E  quad_perm [2,3,0,1]  (xor 2)
//   0xB1  quad_perm [1,0,3,2]  (xor 1)
// These four involutions form a complete butterfly over each aligned
// 16-lane group.
#define DPPF(x, ctrl) \
    __uint_as_float((unsigned)__builtin_amdgcn_update_dpp( \
        0, (int)__float_as_uint(x), (ctrl), 0xF, 0xF, true))

__device__ __forceinline__ void atomic_add_f32(float* p, float v) {
#if defined(__HIP_PLATFORM_AMD__) || defined(__AMDGCN__)
    unsafeAtomicAdd(p, v);   // global_atomic_add_f32, no CAS loop
#else
    atomicAdd(p, v);
#endif
}

// ---------------- h = x @ lin_w + lin_b  (also zeroes out[]) ----------------
// ROUND-0 VERSION, verbatim -- the measured-best configuration (128.97us).
// h-line closed by experiment: r5 proved halving DS/output at equal
// occupancy is neutral (not DS-issue-bound); r3/r4 proved bigger register
// tiles let the compiler software-pipeline VGPRs into an occupancy cliff
// (+11/+12us); r1 proved in-loop s_loads force lgkmcnt(0) drains (+8us).
__global__ __launch_bounds__(256) void h_kernel(
    const float* __restrict__ x,
    const float* __restrict__ lin_w,   // [64,16]
    const float* __restrict__ lin_b,   // [16]
    float* __restrict__ h,             // [N,16]
    float* __restrict__ out,           // [N,16] zero-init
    int n)
{
    __shared__ float s_x [16][IN_C + 4];   // stride 68 floats: 16B-aligned rows
    __shared__ float s_wt[16][IN_C + 4];   // transposed W: s_wt[c][k]

    const int t = threadIdx.x;
    const int nodeBase = blockIdx.x * 16;

    // zero out[] early: store latency hides under the FMA loop below
    {
        const int idx = nodeBase * OUT_C + t;      // 256 consecutive elements
        if (idx < n * OUT_C) out[idx] = 0.0f;
    }

    // stage transposed weights (one-time, conflicts irrelevant)
    for (int i = t; i < IN_C * OUT_C; i += 256)
        s_wt[i & 15][i >> 4] = lin_w[i];

    {
        const int lr = t >> 4;            // row 0..15
        const int k4 = (t & 15) * 4;      // col 0,4,...,60
        const int node = nodeBase + lr;
        float4 v = make_float4(0.f, 0.f, 0.f, 0.f);
        if (node < n) v = *(const float4*)(x + (size_t)node * IN_C + k4);
        *(float4*)(&s_x[lr][k4]) = v;
    }
    __syncthreads();

    const int lr = t >> 4;
    const int c  = t & 15;
    const int node = nodeBase + lr;
    if (node < n) {
        float acc = lin_b[c];
        #pragma unroll
        for (int k4 = 0; k4 < IN_C; k4 += 4) {
            const float4 xv = *(const float4*)(&s_x [lr][k4]);  // broadcast in quad
            const float4 wv = *(const float4*)(&s_wt[c ][k4]);  // <=2-way conflict (free)
            acc = fmaf(xv.x, wv.x, acc);
            acc = fmaf(xv.y, wv.y, acc);
            acc = fmaf(xv.z, wv.z, acc);
            acc = fmaf(xv.w, wv.w, acc);
        }
        h[(size_t)node * OUT_C + c] = acc;
    }
}

// ---------------- per-edge fused kernel: quad-per-edge ----------------
// ROUND-2 VERSION, verbatim -- the measured winner. 16 lanes/edge keeps
// 100k waves of latency-hiding TLP and full-width atomic coalescing
// (16 lanes = one 64B line). r7 proved 8 lanes/edge (half the waves,
// 2 scalar atomics/lane) costs +15us: this kernel is latency/atomic-bound
// (counters: HBM 22%, VALU 29%, occupancy 66%, conflicts 0) and the atomic
// op count is irreducible on gfx950 (no pk f32 atomic -- r6 assembler error).
__global__ __launch_bounds__(256) void edge_kernel(
    const int*   __restrict__ edge_index,  // [2,E]
    const float* __restrict__ edge_attr,   // [E,8]
    const float* __restrict__ ea_w,        // [8,16]
    const float* __restrict__ ea_b,        // [16]
    const float* __restrict__ w1,          // [16]
    const float* __restrict__ b1,          // [16]
    const float* __restrict__ w2,          // [16]
    const float* __restrict__ b2,          // [1]
    const float* __restrict__ h,           // [N,16]
    float*       __restrict__ out,         // [N,16]
    int E)
{
    __shared__ float s_eawT[16][12];   // row c = ea_w[:,c]
    __shared__ float s_eab[OUT_C];

    const int t = threadIdx.x;
    if (t < 128)                s_eawT[t & 15][t >> 4] = ea_w[(t >> 4) * OUT_C + (t & 15)];
    else if (t < 128 + OUT_C)   s_eab[t - 128] = ea_b[t - 128];
    __syncthreads();

    const int gid = blockIdx.x * 256 + t;
    const int e = gid >> 4;
    const int c = gid & 15;
    if (e >= E) return;

    const int row = edge_index[e] - 1;     // edge_index[0][e] - 1
    const int col = edge_index[E + e];     // edge_index[1][e]

    // 32B broadcast per quad (contiguous across the 4 quads of a wave)
    const f32x4* ap = (const f32x4*)(edge_attr + (size_t)e * EA_D);
    const f32x4 a0 = ap[0], a1 = ap[1];

    // gather: 16 consecutive lanes read one 64B line of h
    const float hv = h[(size_t)col * OUT_C + c];

    // agg = h[col][c] * (edge_attr @ ea_w + ea_b)[c]; k ascending (bit-exact
    // vs baseline accumulation order).
    const f32x4 w0 = *(const f32x4*)(&s_eawT[c][0]);
    const f32x4 w4 = *(const f32x4*)(&s_eawT[c][4]);
    float d = s_eab[c];
    d = fmaf(a0.x, w0.x, d);
    d = fmaf(a0.y, w0.y, d);
    d = fmaf(a0.z, w0.z, d);
    d = fmaf(a0.w, w0.w, d);
    d = fmaf(a1.x, w4.x, d);
    d = fmaf(a1.y, w4.y, d);
    d = fmaf(a1.z, w4.z, d);
    d = fmaf(a1.w, w4.w, d);
    const float agg = hv * d;

    // score = b2 + sum_j relu(agg*w1[j]+b1[j])*w2[j]  (uniform scalar loads)
    float s = b2[0];
    #pragma unroll
    for (int j = 0; j < OUT_C; ++j) {
        const float hm = fmaf(agg, w1[j], b1[j]);
        s = fmaf(fmaxf(hm, 0.0f), w2[j], s);
    }

    // softmax over the 16 channels of this quad: DPP butterfly (max then sum)
    float m = s;
    m = fmaxf(m, DPPF(m, 0x140));
    m = fmaxf(m, DPPF(m, 0x141));
    m = fmaxf(m, DPPF(m, 0x4E));
    m = fmaxf(m, DPPF(m, 0xB1));

    const float p = __expf(s - m);
    float den = p;
    den += DPPF(den, 0x140);
    den += DPPF(den, 0x141);
    den += DPPF(den, 0x4E);
    den += DPPF(den, 0xB1);

    const float attn = p * __builtin_amdgcn_rcpf(den);

    // grouped scatter: one 64B line per quad
    atomic_add_f32(out + (size_t)row * OUT_C + c, agg * attn);
}

extern "C" void kernel_launch(void* const* d_in, const int* in_sizes, int n_in,
                              void* d_out, int out_size, void* d_ws, size_t ws_size,
                              hipStream_t stream)
{
    const float* x          = (const float*)d_in[0];
    const int*   edge_index = (const int*)  d_in[1];
    const float* edge_attr  = (const float*)d_in[2];
    const float* lin_w      = (const float*)d_in[3];
    const float* lin_b      = (const float*)d_in[4];
    const float* ea_w       = (const float*)d_in[5];
    const float* ea_b       = (const float*)d_in[6];
    const float* attn_w1    = (const float*)d_in[7];
    const float* attn_b1    = (const float*)d_in[8];
    const float* attn_w2    = (const float*)d_in[9];
    const float* attn_b2    = (const float*)d_in[10];

    const int n = in_sizes[0] / IN_C;      // 100000
    const int E = in_sizes[1] / 2;         // 400000

    float* h   = (float*)d_ws;             // [N,16] = 6.4 MB
    float* out = (float*)d_out;

    // h_kernel zeroes out[] (grid covers every out element exactly once)
    h_kernel<<<(n + 15) / 16, 256, 0, stream>>>(x, lin_w, lin_b, h, out, n);

    // 16 lanes per edge
    const long long threads = (long long)E * OUT_C;
    edge_kernel<<<(int)((threads + 255) / 256), 256, 0, stream>>>(
        edge_index, edge_attr, ea_w, ea_b,
        attn_w1, attn_b1, attn_w2, attn_b2,
        h, out, E);
}